// Round 3
// baseline (769.826 us; speedup 1.0000x reference)
//
#include <hip/hip_runtime.h>

#define EPS 1e-5f
#define SLOPE 0.01f
#define NBMAX 512  // LDS bin capacity (B=500 here; must be >= B)

typedef __attribute__((ext_vector_type(8))) short bf16x8;
typedef __attribute__((ext_vector_type(4))) float f32x4;
typedef __attribute__((ext_vector_type(4))) short s16x4;

__device__ __forceinline__ float leaky(float z) { return z >= 0.f ? z : SLOPE * z; }

// float -> bf16 bits, round-nearest-even
__device__ __forceinline__ short f2bf(float f) {
    unsigned u = __float_as_uint(f);
    u += 0x7fff + ((u >> 16) & 1);
    return (short)(u >> 16);
}

// x [N*64] fp32 -> xb bf16 (streamed, float4)
__global__ __launch_bounds__(256) void k_xcvt(const float* __restrict__ x,
                                              short* __restrict__ xb, int n4) {
    int t = blockIdx.x * 256 + threadIdx.x;
    if (t < n4) {
        f32x4 v = ((const f32x4*)x)[t];
        s16x4 o;
#pragma unroll
        for (int j = 0; j < 4; ++j) o[j] = f2bf(v[j]);
        ((s16x4*)xb)[t] = o;
    }
}

// WT[c][k] = bf16(W1a[k][c])  (transpose so MFMA B-fragments are contiguous)
__global__ __launch_bounds__(256) void k_wprep(const float* __restrict__ W1a,
                                               short* __restrict__ WT) {
    int t = threadIdx.x;
    int c = t >> 1, k0 = (t & 1) * 64;
    for (int k = 0; k < 64; ++k) WT[c * 128 + k0 + k] = f2bf(W1a[(k0 + k) * 128 + c]);
}

// gdst[e] = batch[col[e]]; per-graph histogram via LDS
__global__ __launch_bounds__(256) void k_hist(const int* __restrict__ ei,
                                              const int* __restrict__ batch,
                                              int* __restrict__ gdst,
                                              int* __restrict__ counts, int E) {
    __shared__ int h[NBMAX];
    int t = threadIdx.x;
    for (int b = t; b < NBMAX; b += 256) h[b] = 0;
    __syncthreads();
    int base = blockIdx.x * 4096;
#pragma unroll
    for (int i = 0; i < 16; ++i) {
        int e = base + i * 256 + t;
        if (e < E) {
            int g = batch[ei[E + e]];
            gdst[e] = g;
            atomicAdd(&h[g], 1);
        }
    }
    __syncthreads();
    for (int b = t; b < NBMAX; b += 256)
        if (h[b]) atomicAdd(&counts[b], h[b]);
}

// node_off[g] = first node with batch >= g (batch sorted); node_off[B]=N
__global__ void k_nodeoff(const int* __restrict__ batch, int* __restrict__ node_off,
                          int N, int B) {
    int n = blockIdx.x * blockDim.x + threadIdx.x;
    if (n >= N) return;
    int b1 = batch[n];
    int prev = (n == 0) ? -1 : batch[n - 1];
    for (int g = prev + 1; g <= b1; ++g) node_off[g] = n;
    if (n == N - 1)
        for (int g = b1 + 1; g <= B; ++g) node_off[g] = N;
}

// exclusive scan of counts -> edge_off[0..B]; cursor = edge_off[0..B-1]
__global__ void k_scan(const int* __restrict__ counts, int* __restrict__ edge_off,
                       int* __restrict__ cursor, int B) {
    __shared__ int s[1024];
    int t = threadIdx.x;
    s[t] = (t < B) ? counts[t] : 0;
    __syncthreads();
    for (int d = 1; d < 1024; d <<= 1) {
        int v = (t >= d) ? s[t - d] : 0;
        __syncthreads();
        s[t] += v;
        __syncthreads();
    }
    if (t <= B) {
        int excl = (t == 0) ? 0 : s[t - 1];
        edge_off[t] = excl;
        if (t < B) cursor[t] = excl;
    }
}

// pos_g[e] = destination rank of edge e in graph-sorted order
__global__ __launch_bounds__(256) void k_pos(const int* __restrict__ gdst,
                                             int* __restrict__ cursor,
                                             int* __restrict__ pos_g, int E) {
    __shared__ int cnt[NBMAX];
    __shared__ int basep[NBMAX];
    int t = threadIdx.x;
    for (int b = t; b < NBMAX; b += 256) cnt[b] = 0;
    __syncthreads();
    int blk = blockIdx.x * 4096;
    int g[16], rk[16];
#pragma unroll
    for (int i = 0; i < 16; ++i) {
        int e = blk + i * 256 + t;
        g[i] = (e < E) ? gdst[e] : -1;
        rk[i] = (g[i] >= 0) ? atomicAdd(&cnt[g[i]], 1) : 0;
    }
    __syncthreads();
    for (int b = t; b < NBMAX; b += 256) {
        int c = cnt[b];
        basep[b] = c ? atomicAdd(&cursor[b], c) : 0;
    }
    __syncthreads();
#pragma unroll
    for (int i = 0; i < 16; ++i)
        if (g[i] >= 0) pos_g[blk + i * 256 + t] = basep[g[i]] + rk[i];
}

// Gather-sort: ea_s[pos] = bf16(ea[e]) (coalesced read, 128B-granule scattered
// write), rows_s[pos] = row[e]. 1024 edges/block; 4 rows per wave-iter.
__global__ __launch_bounds__(256) void k_gather(const float* __restrict__ ea,
                                                const int* __restrict__ ei,
                                                const int* __restrict__ pos_g,
                                                short* __restrict__ ea_s,
                                                int* __restrict__ rows_s, int E) {
    int lane = threadIdx.x & 63, wave = threadIdx.x >> 6;
    int r = lane >> 4, c16 = lane & 15;
    int base = blockIdx.x * 1024;
#pragma unroll 4
    for (int eb = wave * 4; eb < 1024; eb += 16) {
        int e = base + eb + r;
        if (e < E) {
            int p = pos_g[e];
            f32x4 v = *(const f32x4*)(ea + (size_t)e * 64 + c16 * 4);
            s16x4 o;
#pragma unroll
            for (int j = 0; j < 4; ++j) o[j] = f2bf(v[j]);
            *(s16x4*)(ea_s + (size_t)p * 64 + c16 * 4) = o;
            if (c16 == 0) rows_s[p] = ei[e];
        }
    }
}

// gx[g][l] = sum over nodes of graph g of x[n][l]  (4 waves per graph)
__global__ __launch_bounds__(256) void k_gx(const float* __restrict__ x,
                                            const int* __restrict__ node_off,
                                            float* __restrict__ gx, int B) {
    __shared__ float part[4][64];
    int g = blockIdx.x, lane = threadIdx.x & 63, wave = threadIdx.x >> 6;
    int n0 = node_off[g], n1 = node_off[g + 1];
    float a = 0.f;
    for (int n = n0 + wave; n < n1; n += 4) a += x[(size_t)n * 64 + lane];
    part[wave][lane] = a;
    __syncthreads();
    if (wave == 0)
        gx[g * 64 + lane] = (part[0][lane] + part[1][lane]) + (part[2][lane] + part[3][lane]);
}

// MFMA edge kernel, full K=128: pre = [x[row] | ea] @ W1a + b1a, all streams
// coalesced except the xb row-gather (6.4 MB, cache-resident).
__global__ __launch_bounds__(256, 2) void k_edges(
    const short* __restrict__ xb, const short* __restrict__ ea_s,
    const int* __restrict__ rows_s, const int* __restrict__ edge_off,
    const short* __restrict__ WT, const float* __restrict__ b1a,
    float* __restrict__ Sg, float* __restrict__ Qg, int CH) {
    const int g = blockIdx.x;
    const int lane = threadIdx.x & 63, wave = threadIdx.x >> 6;
    const int m = lane & 15, quad = lane >> 4;

    // B-fragments: Wf[ks][t] covers K rows ks*32+quad*8..+7, cols t*16+m
    bf16x8 Wf[4][8];
#pragma unroll
    for (int t = 0; t < 8; ++t)
#pragma unroll
        for (int ks = 0; ks < 4; ++ks)
            Wf[ks][t] = *(const bf16x8*)(WT + (t * 16 + m) * 128 + ks * 32 + quad * 8);
    float bb[8];
#pragma unroll
    for (int t = 0; t < 8; ++t) bb[t] = b1a[t * 16 + m];

    const int e0 = edge_off[g], e1 = edge_off[g + 1];
    const int cnt = e1 - e0;
    const int chunk = (cnt + CH - 1) / CH;
    const int lo = e0 + blockIdx.y * chunk;
    const int hi = min(lo + chunk, e1);

    float accS[8] = {0, 0, 0, 0, 0, 0, 0, 0};
    float accQ[8] = {0, 0, 0, 0, 0, 0, 0, 0};

    for (int ib = lo + wave * 16; ib < hi; ib += 64) {
        int idx = min(ib + m, hi - 1);  // clamp tail; masked below
        int rid = rows_s[idx];
        const short* xr = xb + (size_t)rid * 64;
        const short* er = ea_s + (size_t)idx * 64;
        bf16x8 A0 = *(const bf16x8*)(xr + quad * 8);
        bf16x8 A1 = *(const bf16x8*)(xr + 32 + quad * 8);
        bf16x8 A2 = *(const bf16x8*)(er + quad * 8);
        bf16x8 A3 = *(const bf16x8*)(er + 32 + quad * 8);
        float vf[4];
#pragma unroll
        for (int r2 = 0; r2 < 4; ++r2) vf[r2] = ((ib + quad * 4 + r2) < hi) ? 1.f : 0.f;
#pragma unroll
        for (int t = 0; t < 8; ++t) {
            f32x4 c = {0.f, 0.f, 0.f, 0.f};
            c = __builtin_amdgcn_mfma_f32_16x16x32_bf16(A0, Wf[0][t], c, 0, 0, 0);
            c = __builtin_amdgcn_mfma_f32_16x16x32_bf16(A1, Wf[1][t], c, 0, 0, 0);
            c = __builtin_amdgcn_mfma_f32_16x16x32_bf16(A2, Wf[2][t], c, 0, 0, 0);
            c = __builtin_amdgcn_mfma_f32_16x16x32_bf16(A3, Wf[3][t], c, 0, 0, 0);
#pragma unroll
            for (int r2 = 0; r2 < 4; ++r2) {
                float z = c[r2] + bb[t];
                float a = fmaf(SLOPE, fminf(z, 0.f), fmaxf(z, 0.f)) * vf[r2];
                accS[t] += a;
                accQ[t] = fmaf(a, a, accQ[t]);
            }
        }
    }
#pragma unroll
    for (int t = 0; t < 8; ++t) {
        float s = accS[t];
        s += __shfl_xor(s, 16);
        s += __shfl_xor(s, 32);
        float q = accQ[t];
        q += __shfl_xor(q, 16);
        q += __shfl_xor(q, 32);
        if (quad == 0) {
            atomicAdd(&Sg[g * 128 + t * 16 + m], s);
            atomicAdd(&Qg[g * 128 + t * 16 + m], q);
        }
    }
}

// Tail: BN-a stats inline (each block reduces Sg/Qg; L2-resident), then
// T = Sg*sc + cg*sh; ga = T@W2a + cg*b2a; a1 = leaky([gx,ga]@W1b + b1b)
__global__ __launch_bounds__(128) void k_g1(
    const float* __restrict__ Sg, const float* __restrict__ Qg,
    const float* __restrict__ gx, const int* __restrict__ edge_off,
    const float* __restrict__ g1a, const float* __restrict__ be1a,
    const float* __restrict__ W2a, const float* __restrict__ b2a,
    const float* __restrict__ W1b, const float* __restrict__ b1b,
    float* __restrict__ a1, float* __restrict__ sum1, float* __restrict__ sumsq1,
    int B, float invE) {
    __shared__ float T[128];
    __shared__ float gcat[192];
    int g = blockIdx.x, c = threadIdx.x;
    float S = 0.f, Q = 0.f;
    for (int gg = 0; gg < B; ++gg) {
        S += Sg[gg * 128 + c];
        Q += Qg[gg * 128 + c];
    }
    float mn = S * invE;
    float v = Q * invE - mn * mn;
    float sc = g1a[c] * rsqrtf(v + EPS);
    float sh = be1a[c] - mn * sc;
    float cg = (float)(edge_off[g + 1] - edge_off[g]);
    T[c] = Sg[g * 128 + c] * sc + cg * sh;
    if (c < 64) gcat[c] = gx[g * 64 + c];
    __syncthreads();
    float ga = cg * b2a[c];
#pragma unroll 8
    for (int k = 0; k < 128; ++k) ga = fmaf(T[k], W2a[k * 128 + c], ga);
    gcat[64 + c] = ga;
    __syncthreads();
    float z = b1b[c];
#pragma unroll 8
    for (int k = 0; k < 192; ++k) z = fmaf(gcat[k], W1b[k * 128 + c], z);
    float av = leaky(z);
    a1[g * 128 + c] = av;
    atomicAdd(&sum1[c], av);
    atomicAdd(&sumsq1[c], av * av);
}

// hnorm = BN(a_prev); z = hnorm@W + b; optional leaky + next-stats.
__global__ __launch_bounds__(128) void k_bn_lin(
    const float* __restrict__ a_prev, const float* __restrict__ sum,
    const float* __restrict__ sumsq, const float* __restrict__ gma,
    const float* __restrict__ bta, const float* __restrict__ W,
    const float* __restrict__ b, float* __restrict__ a_out,
    float* __restrict__ sum_out, float* __restrict__ sumsq_out, float invB,
    int do_leaky) {
    __shared__ float hs[128];
    int g = blockIdx.x, c = threadIdx.x;
    float mn = sum[c] * invB;
    float v = sumsq[c] * invB - mn * mn;
    float sc = gma[c] * rsqrtf(v + EPS);
    float sh = bta[c] - mn * sc;
    hs[c] = a_prev[g * 128 + c] * sc + sh;
    __syncthreads();
    float z = b[c];
#pragma unroll 8
    for (int k = 0; k < 128; ++k) z = fmaf(hs[k], W[k * 128 + c], z);
    if (do_leaky) {
        z = leaky(z);
        a_out[g * 128 + c] = z;
        atomicAdd(&sum_out[c], z);
        atomicAdd(&sumsq_out[c], z * z);
    } else {
        a_out[g * 128 + c] = z;
    }
}

extern "C" void kernel_launch(void* const* d_in, const int* in_sizes, int n_in,
                              void* d_out, int out_size, void* d_ws, size_t ws_size,
                              hipStream_t stream) {
    const float* x    = (const float*)d_in[0];
    const int*   ei   = (const int*)d_in[1];
    const float* ea   = (const float*)d_in[2];
    const int*   batch= (const int*)d_in[4];
    const float* W1a  = (const float*)d_in[5];
    const float* b1a  = (const float*)d_in[6];
    const float* g1a  = (const float*)d_in[7];
    const float* be1a = (const float*)d_in[8];
    const float* W2a  = (const float*)d_in[9];
    const float* b2a  = (const float*)d_in[10];
    const float* W1b  = (const float*)d_in[11];
    const float* b1b  = (const float*)d_in[12];
    const float* g1b  = (const float*)d_in[13];
    const float* be1b = (const float*)d_in[14];
    const float* W2b  = (const float*)d_in[15];
    const float* b2b  = (const float*)d_in[16];
    const float* g2b  = (const float*)d_in[17];
    const float* be2b = (const float*)d_in[18];
    const float* W3b  = (const float*)d_in[19];
    const float* b3b  = (const float*)d_in[20];

    const int N = in_sizes[0] / 64;
    const int E = in_sizes[1] / 2;
    const int B = in_sizes[3];

    char* ws = (char*)d_ws;
    size_t off = 0;
    auto alloc = [&](size_t bytes) -> char* {
        char* p = ws + off;
        off = (off + bytes + 255) & ~(size_t)255;
        return p;
    };
    // ---- zeroed region (one memset) ----
    int*   counts = (int*)alloc((size_t)B * 4);
    float* Sg     = (float*)alloc((size_t)B * 128 * 4);
    float* Qg     = (float*)alloc((size_t)B * 128 * 4);
    float* sum1   = (float*)alloc(128 * 4);
    float* sumsq1 = (float*)alloc(128 * 4);
    float* sum2   = (float*)alloc(128 * 4);
    float* sumsq2 = (float*)alloc(128 * 4);
    size_t zbytes = off;
    // ---- non-zeroed scratch ----
    short* xb      = (short*)alloc((size_t)N * 64 * 2);
    short* WT      = (short*)alloc(128 * 128 * 2);
    int*   gdst    = (int*)alloc((size_t)E * 4);
    int*   pos_g   = (int*)alloc((size_t)E * 4);
    int*   rows_s  = (int*)alloc((size_t)E * 4);
    short* ea_s    = (short*)alloc((size_t)E * 64 * 2);
    int*   edge_off= (int*)alloc((size_t)(B + 1) * 4);
    int*   cursor  = (int*)alloc((size_t)B * 4);
    int*   node_off= (int*)alloc((size_t)(B + 1) * 4);
    float* gx      = (float*)alloc((size_t)B * 64 * 4);
    float* a1      = (float*)alloc((size_t)B * 128 * 4);
    float* a2      = (float*)alloc((size_t)B * 128 * 4);
    (void)ws_size;
    (void)n_in;

    hipMemsetAsync(ws, 0, zbytes, stream);

    k_xcvt<<<dim3((N * 64 / 4 + 255) / 256), dim3(256), 0, stream>>>(x, xb, N * 16);
    k_wprep<<<dim3(1), dim3(256), 0, stream>>>(W1a, WT);
    k_hist<<<dim3((E + 4095) / 4096), dim3(256), 0, stream>>>(ei, batch, gdst, counts, E);
    k_nodeoff<<<dim3((N + 255) / 256), dim3(256), 0, stream>>>(batch, node_off, N, B);
    k_scan<<<dim3(1), dim3(1024), 0, stream>>>(counts, edge_off, cursor, B);
    k_pos<<<dim3((E + 4095) / 4096), dim3(256), 0, stream>>>(gdst, cursor, pos_g, E);
    k_gather<<<dim3((E + 1023) / 1024), dim3(256), 0, stream>>>(ea, ei, pos_g, ea_s,
                                                                rows_s, E);
    k_gx<<<dim3(B), dim3(256), 0, stream>>>(x, node_off, gx, B);

    const int CH = 8;
    k_edges<<<dim3(B, CH), dim3(256), 0, stream>>>(xb, ea_s, rows_s, edge_off, WT,
                                                   b1a, Sg, Qg, CH);

    k_g1<<<dim3(B), dim3(128), 0, stream>>>(Sg, Qg, gx, edge_off, g1a, be1a, W2a,
                                            b2a, W1b, b1b, a1, sum1, sumsq1, B,
                                            1.0f / (float)E);
    k_bn_lin<<<dim3(B), dim3(128), 0, stream>>>(a1, sum1, sumsq1, g1b, be1b, W2b,
                                                b2b, a2, sum2, sumsq2,
                                                1.0f / (float)B, 1);
    k_bn_lin<<<dim3(B), dim3(128), 0, stream>>>(a2, sum2, sumsq2, g2b, be2b, W3b,
                                                b3b, (float*)d_out, nullptr, nullptr,
                                                1.0f / (float)B, 0);
}

// Round 4
// 580.923 us; speedup vs baseline: 1.3252x; 1.3252x over previous
//
#include <hip/hip_runtime.h>

#define EPS 1e-5f
#define SLOPE 0.01f
#define NBMAX 512  // LDS bin capacity (B=500 here; must be >= B)

typedef __attribute__((ext_vector_type(8))) short bf16x8;
typedef __attribute__((ext_vector_type(4))) float f32x4;
typedef __attribute__((ext_vector_type(4))) short s16x4;

__device__ __forceinline__ float leaky(float z) { return z >= 0.f ? z : SLOPE * z; }

// float -> bf16 bits, round-nearest-even
__device__ __forceinline__ short f2bf(float f) {
    unsigned u = __float_as_uint(f);
    u += 0x7fff + ((u >> 16) & 1);
    return (short)(u >> 16);
}

// Fused prep (independent roles split by blockIdx range):
//  [0, nbx)            : x fp32 -> xb bf16 (streamed)
//  [nbx, nbx+nbh)      : gdst[e] = batch[col[e]] + LDS histogram -> counts
//  [nbx+nbh, +nbn)     : node_off from sorted batch
//  last block          : WT[c][k] = bf16(W1a[k][c])
__global__ __launch_bounds__(256) void k_prep(
    const float* __restrict__ x, short* __restrict__ xb,
    const float* __restrict__ W1a, short* __restrict__ WT,
    const int* __restrict__ ei, const int* __restrict__ batch,
    int* __restrict__ gdst, int* __restrict__ counts, int* __restrict__ node_off,
    int N, int E, int B, int nbx, int nbh, int nbn) {
    __shared__ int h[NBMAX];
    const int bid = blockIdx.x, t = threadIdx.x;
    if (bid < nbx) {
        int i = bid * 256 + t;
        if (i < N * 16) {
            f32x4 v = ((const f32x4*)x)[i];
            s16x4 o;
#pragma unroll
            for (int j = 0; j < 4; ++j) o[j] = f2bf(v[j]);
            ((s16x4*)xb)[i] = o;
        }
    } else if (bid < nbx + nbh) {
        for (int b = t; b < NBMAX; b += 256) h[b] = 0;
        __syncthreads();
        int base = (bid - nbx) * 4096;
#pragma unroll
        for (int i = 0; i < 16; ++i) {
            int e = base + i * 256 + t;
            if (e < E) {
                int g = batch[ei[E + e]];
                gdst[e] = g;
                atomicAdd(&h[g], 1);
            }
        }
        __syncthreads();
        for (int b = t; b < NBMAX; b += 256)
            if (h[b]) atomicAdd(&counts[b], h[b]);
    } else if (bid < nbx + nbh + nbn) {
        int n = (bid - nbx - nbh) * 256 + t;
        if (n < N) {
            int b1 = batch[n];
            int prev = (n == 0) ? -1 : batch[n - 1];
            for (int g = prev + 1; g <= b1; ++g) node_off[g] = n;
            if (n == N - 1)
                for (int g = b1 + 1; g <= B; ++g) node_off[g] = N;
        }
    } else {
        int c = t >> 1, k0 = (t & 1) * 64;
        for (int k = 0; k < 64; ++k)
            WT[c * 128 + k0 + k] = f2bf(W1a[(k0 + k) * 128 + c]);
    }
}

// exclusive scan of counts -> edge_off[0..B]; cursor = edge_off[0..B-1]
__global__ void k_scan(const int* __restrict__ counts, int* __restrict__ edge_off,
                       int* __restrict__ cursor, int B) {
    __shared__ int s[1024];
    int t = threadIdx.x;
    s[t] = (t < B) ? counts[t] : 0;
    __syncthreads();
    for (int d = 1; d < 1024; d <<= 1) {
        int v = (t >= d) ? s[t - d] : 0;
        __syncthreads();
        s[t] += v;
        __syncthreads();
    }
    if (t <= B) {
        int excl = (t == 0) ? 0 : s[t - 1];
        edge_off[t] = excl;
        if (t < B) cursor[t] = excl;
    }
}

// pos_g[e] = destination rank of edge e in graph-sorted order
__global__ __launch_bounds__(256) void k_pos(const int* __restrict__ gdst,
                                             int* __restrict__ cursor,
                                             int* __restrict__ pos_g, int E) {
    __shared__ int cnt[NBMAX];
    __shared__ int basep[NBMAX];
    int t = threadIdx.x;
    for (int b = t; b < NBMAX; b += 256) cnt[b] = 0;
    __syncthreads();
    int blk = blockIdx.x * 4096;
    int g[16], rk[16];
#pragma unroll
    for (int i = 0; i < 16; ++i) {
        int e = blk + i * 256 + t;
        g[i] = (e < E) ? gdst[e] : -1;
        rk[i] = (g[i] >= 0) ? atomicAdd(&cnt[g[i]], 1) : 0;
    }
    __syncthreads();
    for (int b = t; b < NBMAX; b += 256) {
        int c = cnt[b];
        basep[b] = c ? atomicAdd(&cursor[b], c) : 0;
    }
    __syncthreads();
#pragma unroll
    for (int i = 0; i < 16; ++i)
        if (g[i] >= 0) pos_g[blk + i * 256 + t] = basep[g[i]] + rk[i];
}

// Fused: [0, nbg) gather-sort building As[pos] = [xb[row[e]] | bf16(ea[e])]
// (256 B/edge); [nbg, nbg+B) per-graph gx node sums.
__global__ __launch_bounds__(256) void k_gather(
    const float* __restrict__ ea, const short* __restrict__ xb,
    const int* __restrict__ ei, const int* __restrict__ pos_g,
    short* __restrict__ As, const float* __restrict__ x,
    const int* __restrict__ node_off, float* __restrict__ gx, int E, int nbg) {
    const int bid = blockIdx.x;
    const int lane = threadIdx.x & 63, wave = threadIdx.x >> 6;
    if (bid < nbg) {
        int r = lane >> 4, c16 = lane & 15;
        int base = bid * 1024;
#pragma unroll 4
        for (int eb = wave * 4; eb < 1024; eb += 16) {
            int e = base + eb + r;
            if (e < E) {
                int rid = ei[e];
                int p = pos_g[e];
                s16x4 xv = *(const s16x4*)(xb + (size_t)rid * 64 + c16 * 4);
                f32x4 v = *(const f32x4*)(ea + (size_t)e * 64 + c16 * 4);
                s16x4 o;
#pragma unroll
                for (int j = 0; j < 4; ++j) o[j] = f2bf(v[j]);
                short* dst = As + (size_t)p * 128;
                *(s16x4*)(dst + c16 * 4) = xv;
                *(s16x4*)(dst + 64 + c16 * 4) = o;
            }
        }
    } else {
        __shared__ float part[4][64];
        int g = bid - nbg;
        int n0 = node_off[g], n1 = node_off[g + 1];
        float a = 0.f;
        for (int n = n0 + wave; n < n1; n += 4) a += x[(size_t)n * 64 + lane];
        part[wave][lane] = a;
        __syncthreads();
        if (wave == 0)
            gx[g * 64 + lane] =
                (part[0][lane] + part[1][lane]) + (part[2][lane] + part[3][lane]);
    }
}

// MFMA edge kernel — fully streaming: As rows are coalesced, K=128.
// pre = As[idx] @ W1a + b1a; a = leaky(pre); per-graph S/Q in registers.
__global__ __launch_bounds__(256, 2) void k_edges(
    const short* __restrict__ As, const int* __restrict__ edge_off,
    const short* __restrict__ WT, const float* __restrict__ b1a,
    float* __restrict__ Sg, float* __restrict__ Qg, int CH) {
    const int g = blockIdx.x;
    const int lane = threadIdx.x & 63, wave = threadIdx.x >> 6;
    const int m = lane & 15, quad = lane >> 4;

    bf16x8 Wf[4][8];
#pragma unroll
    for (int t = 0; t < 8; ++t)
#pragma unroll
        for (int ks = 0; ks < 4; ++ks)
            Wf[ks][t] = *(const bf16x8*)(WT + (t * 16 + m) * 128 + ks * 32 + quad * 8);
    float bb[8];
#pragma unroll
    for (int t = 0; t < 8; ++t) bb[t] = b1a[t * 16 + m];

    const int e0 = edge_off[g], e1 = edge_off[g + 1];
    const int cnt = e1 - e0;
    const int chunk = (cnt + CH - 1) / CH;
    const int lo = e0 + blockIdx.y * chunk;
    const int hi = min(lo + chunk, e1);

    float accS[8] = {0, 0, 0, 0, 0, 0, 0, 0};
    float accQ[8] = {0, 0, 0, 0, 0, 0, 0, 0};

    for (int ib = lo + wave * 16; ib < hi; ib += 64) {
        int idx = min(ib + m, hi - 1);  // clamp tail; masked below
        const short* arow = As + (size_t)idx * 128;
        bf16x8 A0 = *(const bf16x8*)(arow + quad * 8);
        bf16x8 A1 = *(const bf16x8*)(arow + 32 + quad * 8);
        bf16x8 A2 = *(const bf16x8*)(arow + 64 + quad * 8);
        bf16x8 A3 = *(const bf16x8*)(arow + 96 + quad * 8);
        float vf[4];
#pragma unroll
        for (int r2 = 0; r2 < 4; ++r2) vf[r2] = ((ib + quad * 4 + r2) < hi) ? 1.f : 0.f;
#pragma unroll
        for (int t = 0; t < 8; ++t) {
            f32x4 c = {0.f, 0.f, 0.f, 0.f};
            c = __builtin_amdgcn_mfma_f32_16x16x32_bf16(A0, Wf[0][t], c, 0, 0, 0);
            c = __builtin_amdgcn_mfma_f32_16x16x32_bf16(A1, Wf[1][t], c, 0, 0, 0);
            c = __builtin_amdgcn_mfma_f32_16x16x32_bf16(A2, Wf[2][t], c, 0, 0, 0);
            c = __builtin_amdgcn_mfma_f32_16x16x32_bf16(A3, Wf[3][t], c, 0, 0, 0);
#pragma unroll
            for (int r2 = 0; r2 < 4; ++r2) {
                float z = c[r2] + bb[t];
                float a = fmaf(SLOPE, fminf(z, 0.f), fmaxf(z, 0.f)) * vf[r2];
                accS[t] += a;
                accQ[t] = fmaf(a, a, accQ[t]);
            }
        }
    }
#pragma unroll
    for (int t = 0; t < 8; ++t) {
        float s = accS[t];
        s += __shfl_xor(s, 16);
        s += __shfl_xor(s, 32);
        float q = accQ[t];
        q += __shfl_xor(q, 16);
        q += __shfl_xor(q, 32);
        if (quad == 0) {
            atomicAdd(&Sg[g * 128 + t * 16 + m], s);
            atomicAdd(&Qg[g * 128 + t * 16 + m], q);
        }
    }
}

// Partial reduction of Sg/Qg over graphs (25 blocks)
__global__ __launch_bounds__(128) void k_stats_part(const float* __restrict__ Sg,
                                                    const float* __restrict__ Qg,
                                                    float* __restrict__ Stot,
                                                    float* __restrict__ Qtot, int B) {
    int c = threadIdx.x;
    int per = (B + gridDim.x - 1) / gridDim.x;
    int g0 = blockIdx.x * per, g1 = min(g0 + per, B);
    float S = 0.f, Q = 0.f;
    for (int g = g0; g < g1; ++g) {
        S += Sg[g * 128 + c];
        Q += Qg[g * 128 + c];
    }
    atomicAdd(&Stot[c], S);
    atomicAdd(&Qtot[c], Q);
}

// T = Sg*sc + cg*sh (sc/sh from Stot/Qtot); ga = T@W2a + cg*b2a;
// a1 = leaky([gx,ga]@W1b + b1b); accumulate BN1b stats.
__global__ __launch_bounds__(128) void k_g1(
    const float* __restrict__ Sg, const float* __restrict__ Stot,
    const float* __restrict__ Qtot, const float* __restrict__ gx,
    const int* __restrict__ edge_off, const float* __restrict__ g1a,
    const float* __restrict__ be1a, const float* __restrict__ W2a,
    const float* __restrict__ b2a, const float* __restrict__ W1b,
    const float* __restrict__ b1b, float* __restrict__ a1,
    float* __restrict__ sum1, float* __restrict__ sumsq1, float invE) {
    __shared__ float T[128];
    __shared__ float gcat[192];
    int g = blockIdx.x, c = threadIdx.x;
    float mn = Stot[c] * invE;
    float v = Qtot[c] * invE - mn * mn;
    float sc = g1a[c] * rsqrtf(v + EPS);
    float sh = be1a[c] - mn * sc;
    float cg = (float)(edge_off[g + 1] - edge_off[g]);
    T[c] = Sg[g * 128 + c] * sc + cg * sh;
    if (c < 64) gcat[c] = gx[g * 64 + c];
    __syncthreads();
    float ga = cg * b2a[c];
#pragma unroll 8
    for (int k = 0; k < 128; ++k) ga = fmaf(T[k], W2a[k * 128 + c], ga);
    gcat[64 + c] = ga;
    __syncthreads();
    float z = b1b[c];
#pragma unroll 8
    for (int k = 0; k < 192; ++k) z = fmaf(gcat[k], W1b[k * 128 + c], z);
    float av = leaky(z);
    a1[g * 128 + c] = av;
    atomicAdd(&sum1[c], av);
    atomicAdd(&sumsq1[c], av * av);
}

// hnorm = BN(a_prev); z = hnorm@W + b; optional leaky + next-stats.
__global__ __launch_bounds__(128) void k_bn_lin(
    const float* __restrict__ a_prev, const float* __restrict__ sum,
    const float* __restrict__ sumsq, const float* __restrict__ gma,
    const float* __restrict__ bta, const float* __restrict__ W,
    const float* __restrict__ b, float* __restrict__ a_out,
    float* __restrict__ sum_out, float* __restrict__ sumsq_out, float invB,
    int do_leaky) {
    __shared__ float hs[128];
    int g = blockIdx.x, c = threadIdx.x;
    float mn = sum[c] * invB;
    float v = sumsq[c] * invB - mn * mn;
    float sc = gma[c] * rsqrtf(v + EPS);
    float sh = bta[c] - mn * sc;
    hs[c] = a_prev[g * 128 + c] * sc + sh;
    __syncthreads();
    float z = b[c];
#pragma unroll 8
    for (int k = 0; k < 128; ++k) z = fmaf(hs[k], W[k * 128 + c], z);
    if (do_leaky) {
        z = leaky(z);
        a_out[g * 128 + c] = z;
        atomicAdd(&sum_out[c], z);
        atomicAdd(&sumsq_out[c], z * z);
    } else {
        a_out[g * 128 + c] = z;
    }
}

extern "C" void kernel_launch(void* const* d_in, const int* in_sizes, int n_in,
                              void* d_out, int out_size, void* d_ws, size_t ws_size,
                              hipStream_t stream) {
    const float* x    = (const float*)d_in[0];
    const int*   ei   = (const int*)d_in[1];
    const float* ea   = (const float*)d_in[2];
    const int*   batch= (const int*)d_in[4];
    const float* W1a  = (const float*)d_in[5];
    const float* b1a  = (const float*)d_in[6];
    const float* g1a  = (const float*)d_in[7];
    const float* be1a = (const float*)d_in[8];
    const float* W2a  = (const float*)d_in[9];
    const float* b2a  = (const float*)d_in[10];
    const float* W1b  = (const float*)d_in[11];
    const float* b1b  = (const float*)d_in[12];
    const float* g1b  = (const float*)d_in[13];
    const float* be1b = (const float*)d_in[14];
    const float* W2b  = (const float*)d_in[15];
    const float* b2b  = (const float*)d_in[16];
    const float* g2b  = (const float*)d_in[17];
    const float* be2b = (const float*)d_in[18];
    const float* W3b  = (const float*)d_in[19];
    const float* b3b  = (const float*)d_in[20];

    const int N = in_sizes[0] / 64;
    const int E = in_sizes[1] / 2;
    const int B = in_sizes[3];

    char* ws = (char*)d_ws;
    size_t off = 0;
    auto alloc = [&](size_t bytes) -> char* {
        char* p = ws + off;
        off = (off + bytes + 255) & ~(size_t)255;
        return p;
    };
    // ---- zeroed region (one memset) ----
    int*   counts = (int*)alloc((size_t)B * 4);
    float* Sg     = (float*)alloc((size_t)B * 128 * 4);
    float* Qg     = (float*)alloc((size_t)B * 128 * 4);
    float* sum1   = (float*)alloc(128 * 4);
    float* sumsq1 = (float*)alloc(128 * 4);
    float* sum2   = (float*)alloc(128 * 4);
    float* sumsq2 = (float*)alloc(128 * 4);
    float* Stot   = (float*)alloc(128 * 4);
    float* Qtot   = (float*)alloc(128 * 4);
    size_t zbytes = off;
    // ---- non-zeroed scratch ----
    short* xb      = (short*)alloc((size_t)N * 64 * 2);
    short* WT      = (short*)alloc(128 * 128 * 2);
    int*   gdst    = (int*)alloc((size_t)E * 4);
    int*   pos_g   = (int*)alloc((size_t)E * 4);
    short* As      = (short*)alloc((size_t)E * 128 * 2);
    int*   edge_off= (int*)alloc((size_t)(B + 1) * 4);
    int*   cursor  = (int*)alloc((size_t)B * 4);
    int*   node_off= (int*)alloc((size_t)(B + 1) * 4);
    float* gx      = (float*)alloc((size_t)B * 64 * 4);
    float* a1      = (float*)alloc((size_t)B * 128 * 4);
    float* a2      = (float*)alloc((size_t)B * 128 * 4);
    (void)ws_size;
    (void)n_in;

    hipMemsetAsync(ws, 0, zbytes, stream);

    const int nbx = (N * 16 + 255) / 256;
    const int nbh = (E + 4095) / 4096;
    const int nbn = (N + 255) / 256;
    k_prep<<<dim3(nbx + nbh + nbn + 1), dim3(256), 0, stream>>>(
        x, xb, W1a, WT, ei, batch, gdst, counts, node_off, N, E, B, nbx, nbh, nbn);
    k_scan<<<dim3(1), dim3(1024), 0, stream>>>(counts, edge_off, cursor, B);
    k_pos<<<dim3(nbh), dim3(256), 0, stream>>>(gdst, cursor, pos_g, E);
    const int nbg = (E + 1023) / 1024;
    k_gather<<<dim3(nbg + B), dim3(256), 0, stream>>>(ea, xb, ei, pos_g, As, x,
                                                      node_off, gx, E, nbg);
    const int CH = 8;
    k_edges<<<dim3(B, CH), dim3(256), 0, stream>>>(As, edge_off, WT, b1a, Sg, Qg, CH);
    k_stats_part<<<dim3(25), dim3(128), 0, stream>>>(Sg, Qg, Stot, Qtot, B);
    k_g1<<<dim3(B), dim3(128), 0, stream>>>(Sg, Stot, Qtot, gx, edge_off, g1a, be1a,
                                            W2a, b2a, W1b, b1b, a1, sum1, sumsq1,
                                            1.0f / (float)E);
    k_bn_lin<<<dim3(B), dim3(128), 0, stream>>>(a1, sum1, sumsq1, g1b, be1b, W2b,
                                                b2b, a2, sum2, sumsq2,
                                                1.0f / (float)B, 1);
    k_bn_lin<<<dim3(B), dim3(128), 0, stream>>>(a2, sum2, sumsq2, g2b, be2b, W3b,
                                                b3b, (float*)d_out, nullptr, nullptr,
                                                1.0f / (float)B, 0);
}

// Round 5
// 481.662 us; speedup vs baseline: 1.5983x; 1.2061x over previous
//
#include <hip/hip_runtime.h>

#define EPS 1e-5f
#define SLOPE 0.01f
#define NBMAX 512  // LDS bin capacity (B=500 here; must be >= B)

typedef __attribute__((ext_vector_type(8))) short bf16x8;
typedef __attribute__((ext_vector_type(4))) float f32x4;
typedef __attribute__((ext_vector_type(4))) short s16x4;

__device__ __forceinline__ float leaky(float z) { return z >= 0.f ? z : SLOPE * z; }

// float -> bf16 bits, round-nearest-even (used in prep, off hot path)
__device__ __forceinline__ short f2bf(float f) {
    unsigned u = __float_as_uint(f);
    u += 0x7fff + ((u >> 16) & 1);
    return (short)(u >> 16);
}

// two floats -> packed bf16 pair, round-half-up (1 add/float + 1 v_perm)
__device__ __forceinline__ unsigned pack2(float f0, float f1) {
    unsigned u0 = __float_as_uint(f0) + 0x8000u;
    unsigned u1 = __float_as_uint(f1) + 0x8000u;
    return __builtin_amdgcn_perm(u1, u0, 0x07060302u);  // (bf(f1)<<16)|bf(f0)
}
__device__ __forceinline__ bf16x8 pack8(f32x4 lo, f32x4 hi) {
    union { bf16x8 v; unsigned u[4]; } r;
    r.u[0] = pack2(lo[0], lo[1]);
    r.u[1] = pack2(lo[2], lo[3]);
    r.u[2] = pack2(hi[0], hi[1]);
    r.u[3] = pack2(hi[2], hi[3]);
    return r.v;
}

// Fused prep (independent roles split by blockIdx range):
//  [0, nbx)        : x fp32 -> xb bf16 (streamed)
//  [nbx, nbx+nbh)  : gdst[e] = batch[col[e]] + LDS histogram -> counts
//  [nbx+nbh, +nbn) : node_off from sorted batch
//  last block      : WT[c][k] = bf16(W1a[k][c])
__global__ __launch_bounds__(256) void k_prep(
    const float* __restrict__ x, short* __restrict__ xb,
    const float* __restrict__ W1a, short* __restrict__ WT,
    const int* __restrict__ ei, const int* __restrict__ batch,
    int* __restrict__ gdst, int* __restrict__ counts, int* __restrict__ node_off,
    int N, int E, int B, int nbx, int nbh, int nbn) {
    __shared__ int h[NBMAX];
    const int bid = blockIdx.x, t = threadIdx.x;
    if (bid < nbx) {
        int i = bid * 256 + t;
        if (i < N * 16) {
            f32x4 v = ((const f32x4*)x)[i];
            s16x4 o;
#pragma unroll
            for (int j = 0; j < 4; ++j) o[j] = f2bf(v[j]);
            ((s16x4*)xb)[i] = o;
        }
    } else if (bid < nbx + nbh) {
        for (int b = t; b < NBMAX; b += 256) h[b] = 0;
        __syncthreads();
        int base = (bid - nbx) * 4096;
#pragma unroll
        for (int i = 0; i < 16; ++i) {
            int e = base + i * 256 + t;
            if (e < E) {
                int g = batch[ei[E + e]];
                gdst[e] = g;
                atomicAdd(&h[g], 1);
            }
        }
        __syncthreads();
        for (int b = t; b < NBMAX; b += 256)
            if (h[b]) atomicAdd(&counts[b], h[b]);
    } else if (bid < nbx + nbh + nbn) {
        int n = (bid - nbx - nbh) * 256 + t;
        if (n < N) {
            int b1 = batch[n];
            int prev = (n == 0) ? -1 : batch[n - 1];
            for (int g = prev + 1; g <= b1; ++g) node_off[g] = n;
            if (n == N - 1)
                for (int g = b1 + 1; g <= B; ++g) node_off[g] = N;
        }
    } else {
        int c = t >> 1, k0 = (t & 1) * 64;
        for (int k = 0; k < 64; ++k)
            WT[c * 128 + k0 + k] = f2bf(W1a[(k0 + k) * 128 + c]);
    }
}

// exclusive scan of counts -> edge_off[0..B]; cursor = edge_off[0..B-1]
__global__ void k_scan(const int* __restrict__ counts, int* __restrict__ edge_off,
                       int* __restrict__ cursor, int B) {
    __shared__ int s[1024];
    int t = threadIdx.x;
    s[t] = (t < B) ? counts[t] : 0;
    __syncthreads();
    for (int d = 1; d < 1024; d <<= 1) {
        int v = (t >= d) ? s[t - d] : 0;
        __syncthreads();
        s[t] += v;
        __syncthreads();
    }
    if (t <= B) {
        int excl = (t == 0) ? 0 : s[t - 1];
        edge_off[t] = excl;
        if (t < B) cursor[t] = excl;
    }
}

// Fused: [0, nbh) counting-sort placement: perm[pos]=e, rows_s[pos]=ei[e]
// (ei read coalesced; 4 B scattered writes). [nbh, nbh+B): gx node sums.
__global__ __launch_bounds__(256) void k_pos(
    const int* __restrict__ gdst, const int* __restrict__ ei,
    int* __restrict__ cursor, int* __restrict__ perm, int* __restrict__ rows_s,
    const float* __restrict__ x, const int* __restrict__ node_off,
    float* __restrict__ gx, int E, int nbh) {
    __shared__ int cnt[NBMAX];
    __shared__ int basep[NBMAX];
    __shared__ float part[4][64];
    const int bid = blockIdx.x, t = threadIdx.x;
    if (bid < nbh) {
        for (int b = t; b < NBMAX; b += 256) cnt[b] = 0;
        __syncthreads();
        int blk = bid * 4096;
        int g[16], rk[16];
#pragma unroll
        for (int i = 0; i < 16; ++i) {
            int e = blk + i * 256 + t;
            g[i] = (e < E) ? gdst[e] : -1;
            rk[i] = (g[i] >= 0) ? atomicAdd(&cnt[g[i]], 1) : 0;
        }
        __syncthreads();
        for (int b = t; b < NBMAX; b += 256) {
            int c = cnt[b];
            basep[b] = c ? atomicAdd(&cursor[b], c) : 0;
        }
        __syncthreads();
#pragma unroll
        for (int i = 0; i < 16; ++i) {
            int e = blk + i * 256 + t;
            if (g[i] >= 0) {
                int pos = basep[g[i]] + rk[i];
                perm[pos] = e;
                rows_s[pos] = ei[e];
            }
        }
    } else {
        int g = bid - nbh;
        int lane = t & 63, wave = t >> 6;
        int n0 = node_off[g], n1 = node_off[g + 1];
        float a = 0.f;
        for (int n = n0 + wave; n < n1; n += 4) a += x[(size_t)n * 64 + lane];
        part[wave][lane] = a;
        __syncthreads();
        if (wave == 0)
            gx[g * 64 + lane] =
                (part[0][lane] + part[1][lane]) + (part[2][lane] + part[3][lane]);
    }
}

// Fused gather + MFMA edge kernel (no As materialization).
// Per 16-edge tile: coalesced rows_s/perm, xb row-gather (bf16, cached),
// ea row-gather (fp32 -> bf16 in-register), 32 MFMA, leaky+S/Q accumulate.
__global__ __launch_bounds__(256) void k_edges2(
    const short* __restrict__ xb, const float* __restrict__ ea,
    const int* __restrict__ rows_s, const int* __restrict__ perm,
    const int* __restrict__ edge_off, const short* __restrict__ WT,
    const float* __restrict__ b1a, float* __restrict__ Sg, float* __restrict__ Qg,
    int CH) {
    const int g = blockIdx.x;
    const int lane = threadIdx.x & 63, wave = threadIdx.x >> 6;
    const int m = lane & 15, quad = lane >> 4;

    bf16x8 Wf[4][8];
#pragma unroll
    for (int t = 0; t < 8; ++t)
#pragma unroll
        for (int ks = 0; ks < 4; ++ks)
            Wf[ks][t] = *(const bf16x8*)(WT + (t * 16 + m) * 128 + ks * 32 + quad * 8);
    float bb[8];
#pragma unroll
    for (int t = 0; t < 8; ++t) bb[t] = b1a[t * 16 + m];

    const int e0 = edge_off[g], e1 = edge_off[g + 1];
    const int cnt = e1 - e0;
    const int chunk = (cnt + CH - 1) / CH;
    const int lo = e0 + blockIdx.y * chunk;
    const int hi = min(lo + chunk, e1);

    float accS[8] = {0, 0, 0, 0, 0, 0, 0, 0};
    float accQ[8] = {0, 0, 0, 0, 0, 0, 0, 0};

    for (int ib = lo + wave * 16; ib < hi; ib += 64) {
        int idx = min(ib + m, hi - 1);  // clamp tail; masked below
        int rid = rows_s[idx];
        int e = perm[idx];
        const short* xr = xb + (size_t)rid * 64;
        bf16x8 A0 = *(const bf16x8*)(xr + quad * 8);
        bf16x8 A1 = *(const bf16x8*)(xr + 32 + quad * 8);
        const float* er = ea + (size_t)e * 64;
        f32x4 p0 = *(const f32x4*)(er + quad * 8);
        f32x4 p1 = *(const f32x4*)(er + quad * 8 + 4);
        f32x4 p2 = *(const f32x4*)(er + 32 + quad * 8);
        f32x4 p3 = *(const f32x4*)(er + 32 + quad * 8 + 4);
        bf16x8 A2 = pack8(p0, p1);
        bf16x8 A3 = pack8(p2, p3);
        if (ib + 16 <= hi) {  // full tile: no masking
#pragma unroll
            for (int t = 0; t < 8; ++t) {
                f32x4 c = {0.f, 0.f, 0.f, 0.f};
                c = __builtin_amdgcn_mfma_f32_16x16x32_bf16(A0, Wf[0][t], c, 0, 0, 0);
                c = __builtin_amdgcn_mfma_f32_16x16x32_bf16(A1, Wf[1][t], c, 0, 0, 0);
                c = __builtin_amdgcn_mfma_f32_16x16x32_bf16(A2, Wf[2][t], c, 0, 0, 0);
                c = __builtin_amdgcn_mfma_f32_16x16x32_bf16(A3, Wf[3][t], c, 0, 0, 0);
#pragma unroll
                for (int r2 = 0; r2 < 4; ++r2) {
                    float z = c[r2] + bb[t];
                    float a = fmaf(SLOPE, fminf(z, 0.f), fmaxf(z, 0.f));
                    accS[t] += a;
                    accQ[t] = fmaf(a, a, accQ[t]);
                }
            }
        } else {
            float vf[4];
#pragma unroll
            for (int r2 = 0; r2 < 4; ++r2)
                vf[r2] = ((ib + quad * 4 + r2) < hi) ? 1.f : 0.f;
#pragma unroll
            for (int t = 0; t < 8; ++t) {
                f32x4 c = {0.f, 0.f, 0.f, 0.f};
                c = __builtin_amdgcn_mfma_f32_16x16x32_bf16(A0, Wf[0][t], c, 0, 0, 0);
                c = __builtin_amdgcn_mfma_f32_16x16x32_bf16(A1, Wf[1][t], c, 0, 0, 0);
                c = __builtin_amdgcn_mfma_f32_16x16x32_bf16(A2, Wf[2][t], c, 0, 0, 0);
                c = __builtin_amdgcn_mfma_f32_16x16x32_bf16(A3, Wf[3][t], c, 0, 0, 0);
#pragma unroll
                for (int r2 = 0; r2 < 4; ++r2) {
                    float z = c[r2] + bb[t];
                    float a = fmaf(SLOPE, fminf(z, 0.f), fmaxf(z, 0.f)) * vf[r2];
                    accS[t] += a;
                    accQ[t] = fmaf(a, a, accQ[t]);
                }
            }
        }
    }
#pragma unroll
    for (int t = 0; t < 8; ++t) {
        float s = accS[t];
        s += __shfl_xor(s, 16);
        s += __shfl_xor(s, 32);
        float q = accQ[t];
        q += __shfl_xor(q, 16);
        q += __shfl_xor(q, 32);
        if (quad == 0) {
            atomicAdd(&Sg[g * 128 + t * 16 + m], s);
            atomicAdd(&Qg[g * 128 + t * 16 + m], q);
        }
    }
}

// Partial reduction of Sg/Qg over graphs (25 blocks)
__global__ __launch_bounds__(128) void k_stats_part(const float* __restrict__ Sg,
                                                    const float* __restrict__ Qg,
                                                    float* __restrict__ Stot,
                                                    float* __restrict__ Qtot, int B) {
    int c = threadIdx.x;
    int per = (B + gridDim.x - 1) / gridDim.x;
    int g0 = blockIdx.x * per, g1 = min(g0 + per, B);
    float S = 0.f, Q = 0.f;
    for (int g = g0; g < g1; ++g) {
        S += Sg[g * 128 + c];
        Q += Qg[g * 128 + c];
    }
    atomicAdd(&Stot[c], S);
    atomicAdd(&Qtot[c], Q);
}

// T = Sg*sc + cg*sh (sc/sh from Stot/Qtot); ga = T@W2a + cg*b2a;
// a1 = leaky([gx,ga]@W1b + b1b); accumulate BN1b stats.
__global__ __launch_bounds__(128) void k_g1(
    const float* __restrict__ Sg, const float* __restrict__ Stot,
    const float* __restrict__ Qtot, const float* __restrict__ gx,
    const int* __restrict__ edge_off, const float* __restrict__ g1a,
    const float* __restrict__ be1a, const float* __restrict__ W2a,
    const float* __restrict__ b2a, const float* __restrict__ W1b,
    const float* __restrict__ b1b, float* __restrict__ a1,
    float* __restrict__ sum1, float* __restrict__ sumsq1, float invE) {
    __shared__ float T[128];
    __shared__ float gcat[192];
    int g = blockIdx.x, c = threadIdx.x;
    float mn = Stot[c] * invE;
    float v = Qtot[c] * invE - mn * mn;
    float sc = g1a[c] * rsqrtf(v + EPS);
    float sh = be1a[c] - mn * sc;
    float cg = (float)(edge_off[g + 1] - edge_off[g]);
    T[c] = Sg[g * 128 + c] * sc + cg * sh;
    if (c < 64) gcat[c] = gx[g * 64 + c];
    __syncthreads();
    float ga = cg * b2a[c];
#pragma unroll 8
    for (int k = 0; k < 128; ++k) ga = fmaf(T[k], W2a[k * 128 + c], ga);
    gcat[64 + c] = ga;
    __syncthreads();
    float z = b1b[c];
#pragma unroll 8
    for (int k = 0; k < 192; ++k) z = fmaf(gcat[k], W1b[k * 128 + c], z);
    float av = leaky(z);
    a1[g * 128 + c] = av;
    atomicAdd(&sum1[c], av);
    atomicAdd(&sumsq1[c], av * av);
}

// hnorm = BN(a_prev); z = hnorm@W + b; optional leaky + next-stats.
__global__ __launch_bounds__(128) void k_bn_lin(
    const float* __restrict__ a_prev, const float* __restrict__ sum,
    const float* __restrict__ sumsq, const float* __restrict__ gma,
    const float* __restrict__ bta, const float* __restrict__ W,
    const float* __restrict__ b, float* __restrict__ a_out,
    float* __restrict__ sum_out, float* __restrict__ sumsq_out, float invB,
    int do_leaky) {
    __shared__ float hs[128];
    int g = blockIdx.x, c = threadIdx.x;
    float mn = sum[c] * invB;
    float v = sumsq[c] * invB - mn * mn;
    float sc = gma[c] * rsqrtf(v + EPS);
    float sh = bta[c] - mn * sc;
    hs[c] = a_prev[g * 128 + c] * sc + sh;
    __syncthreads();
    float z = b[c];
#pragma unroll 8
    for (int k = 0; k < 128; ++k) z = fmaf(hs[k], W[k * 128 + c], z);
    if (do_leaky) {
        z = leaky(z);
        a_out[g * 128 + c] = z;
        atomicAdd(&sum_out[c], z);
        atomicAdd(&sumsq_out[c], z * z);
    } else {
        a_out[g * 128 + c] = z;
    }
}

extern "C" void kernel_launch(void* const* d_in, const int* in_sizes, int n_in,
                              void* d_out, int out_size, void* d_ws, size_t ws_size,
                              hipStream_t stream) {
    const float* x    = (const float*)d_in[0];
    const int*   ei   = (const int*)d_in[1];
    const float* ea   = (const float*)d_in[2];
    const int*   batch= (const int*)d_in[4];
    const float* W1a  = (const float*)d_in[5];
    const float* b1a  = (const float*)d_in[6];
    const float* g1a  = (const float*)d_in[7];
    const float* be1a = (const float*)d_in[8];
    const float* W2a  = (const float*)d_in[9];
    const float* b2a  = (const float*)d_in[10];
    const float* W1b  = (const float*)d_in[11];
    const float* b1b  = (const float*)d_in[12];
    const float* g1b  = (const float*)d_in[13];
    const float* be1b = (const float*)d_in[14];
    const float* W2b  = (const float*)d_in[15];
    const float* b2b  = (const float*)d_in[16];
    const float* g2b  = (const float*)d_in[17];
    const float* be2b = (const float*)d_in[18];
    const float* W3b  = (const float*)d_in[19];
    const float* b3b  = (const float*)d_in[20];

    const int N = in_sizes[0] / 64;
    const int E = in_sizes[1] / 2;
    const int B = in_sizes[3];

    char* ws = (char*)d_ws;
    size_t off = 0;
    auto alloc = [&](size_t bytes) -> char* {
        char* p = ws + off;
        off = (off + bytes + 255) & ~(size_t)255;
        return p;
    };
    // ---- zeroed region (one memset) ----
    int*   counts = (int*)alloc((size_t)B * 4);
    float* Sg     = (float*)alloc((size_t)B * 128 * 4);
    float* Qg     = (float*)alloc((size_t)B * 128 * 4);
    float* sum1   = (float*)alloc(128 * 4);
    float* sumsq1 = (float*)alloc(128 * 4);
    float* sum2   = (float*)alloc(128 * 4);
    float* sumsq2 = (float*)alloc(128 * 4);
    float* Stot   = (float*)alloc(128 * 4);
    float* Qtot   = (float*)alloc(128 * 4);
    size_t zbytes = off;
    // ---- non-zeroed scratch ----
    short* xb      = (short*)alloc((size_t)N * 64 * 2);
    short* WT      = (short*)alloc(128 * 128 * 2);
    int*   gdst    = (int*)alloc((size_t)E * 4);
    int*   perm    = (int*)alloc((size_t)E * 4);
    int*   rows_s  = (int*)alloc((size_t)E * 4);
    int*   edge_off= (int*)alloc((size_t)(B + 1) * 4);
    int*   cursor  = (int*)alloc((size_t)B * 4);
    int*   node_off= (int*)alloc((size_t)(B + 1) * 4);
    float* gx      = (float*)alloc((size_t)B * 64 * 4);
    float* a1      = (float*)alloc((size_t)B * 128 * 4);
    float* a2      = (float*)alloc((size_t)B * 128 * 4);
    (void)ws_size;
    (void)n_in;

    hipMemsetAsync(ws, 0, zbytes, stream);

    const int nbx = (N * 16 + 255) / 256;
    const int nbh = (E + 4095) / 4096;
    const int nbn = (N + 255) / 256;
    k_prep<<<dim3(nbx + nbh + nbn + 1), dim3(256), 0, stream>>>(
        x, xb, W1a, WT, ei, batch, gdst, counts, node_off, N, E, B, nbx, nbh, nbn);
    k_scan<<<dim3(1), dim3(1024), 0, stream>>>(counts, edge_off, cursor, B);
    k_pos<<<dim3(nbh + B), dim3(256), 0, stream>>>(gdst, ei, cursor, perm, rows_s,
                                                   x, node_off, gx, E, nbh);
    const int CH = 2;
    k_edges2<<<dim3(B, CH), dim3(256), 0, stream>>>(xb, ea, rows_s, perm, edge_off,
                                                    WT, b1a, Sg, Qg, CH);
    k_stats_part<<<dim3(25), dim3(128), 0, stream>>>(Sg, Qg, Stot, Qtot, B);
    k_g1<<<dim3(B), dim3(128), 0, stream>>>(Sg, Stot, Qtot, gx, edge_off, g1a, be1a,
                                            W2a, b2a, W1b, b1b, a1, sum1, sumsq1,
                                            1.0f / (float)E);
    k_bn_lin<<<dim3(B), dim3(128), 0, stream>>>(a1, sum1, sumsq1, g1b, be1b, W2b,
                                                b2b, a2, sum2, sumsq2,
                                                1.0f / (float)B, 1);
    k_bn_lin<<<dim3(B), dim3(128), 0, stream>>>(a2, sum2, sumsq2, g2b, be2b, W3b,
                                                b3b, (float*)d_out, nullptr, nullptr,
                                                1.0f / (float)B, 0);
}

// Round 6
// 470.177 us; speedup vs baseline: 1.6373x; 1.0244x over previous
//
#include <hip/hip_runtime.h>

#define EPS 1e-5f
#define SLOPE 0.01f
#define NBMAX 512  // LDS bin capacity (B=500 here; must be >= B)

typedef __attribute__((ext_vector_type(8))) short bf16x8;
typedef __attribute__((ext_vector_type(4))) float f32x4;
typedef __attribute__((ext_vector_type(4))) short s16x4;

__device__ __forceinline__ float leaky(float z) { return z >= 0.f ? z : SLOPE * z; }

// float -> bf16 bits, round-nearest-even (used in prep, off hot path)
__device__ __forceinline__ short f2bf(float f) {
    unsigned u = __float_as_uint(f);
    u += 0x7fff + ((u >> 16) & 1);
    return (short)(u >> 16);
}

// two floats -> packed bf16 pair, round-half-up (1 add/float + 1 v_perm)
__device__ __forceinline__ unsigned pack2(float f0, float f1) {
    unsigned u0 = __float_as_uint(f0) + 0x8000u;
    unsigned u1 = __float_as_uint(f1) + 0x8000u;
    return __builtin_amdgcn_perm(u1, u0, 0x07060302u);  // (bf(f1)<<16)|bf(f0)
}
__device__ __forceinline__ bf16x8 pack8(f32x4 lo, f32x4 hi) {
    union { bf16x8 v; unsigned u[4]; } r;
    r.u[0] = pack2(lo[0], lo[1]);
    r.u[1] = pack2(lo[2], lo[3]);
    r.u[2] = pack2(hi[0], hi[1]);
    r.u[3] = pack2(hi[2], hi[3]);
    return r.v;
}

// Fused prep (independent roles split by blockIdx range):
//  [0, nbx)        : x fp32 -> xb bf16 (streamed)
//  [nbx, nbx+nbh)  : gdst[e] = batch[col[e]] + LDS histogram -> counts
//  [nbx+nbh, +nbn) : node_off from sorted batch
//  last block      : WT[c][k] = bf16(W1a[k][c])
__global__ __launch_bounds__(256) void k_prep(
    const float* __restrict__ x, short* __restrict__ xb,
    const float* __restrict__ W1a, short* __restrict__ WT,
    const int* __restrict__ ei, const int* __restrict__ batch,
    int* __restrict__ gdst, int* __restrict__ counts, int* __restrict__ node_off,
    int N, int E, int B, int nbx, int nbh, int nbn) {
    __shared__ int h[NBMAX];
    const int bid = blockIdx.x, t = threadIdx.x;
    if (bid < nbx) {
        int i = bid * 256 + t;
        if (i < N * 16) {
            f32x4 v = ((const f32x4*)x)[i];
            s16x4 o;
#pragma unroll
            for (int j = 0; j < 4; ++j) o[j] = f2bf(v[j]);
            ((s16x4*)xb)[i] = o;
        }
    } else if (bid < nbx + nbh) {
        for (int b = t; b < NBMAX; b += 256) h[b] = 0;
        __syncthreads();
        int base = (bid - nbx) * 4096;
#pragma unroll
        for (int i = 0; i < 16; ++i) {
            int e = base + i * 256 + t;
            if (e < E) {
                int g = batch[ei[E + e]];
                gdst[e] = g;
                atomicAdd(&h[g], 1);
            }
        }
        __syncthreads();
        for (int b = t; b < NBMAX; b += 256)
            if (h[b]) atomicAdd(&counts[b], h[b]);
    } else if (bid < nbx + nbh + nbn) {
        int n = (bid - nbx - nbh) * 256 + t;
        if (n < N) {
            int b1 = batch[n];
            int prev = (n == 0) ? -1 : batch[n - 1];
            for (int g = prev + 1; g <= b1; ++g) node_off[g] = n;
            if (n == N - 1)
                for (int g = b1 + 1; g <= B; ++g) node_off[g] = N;
        }
    } else {
        int c = t >> 1, k0 = (t & 1) * 64;
        for (int k = 0; k < 64; ++k)
            WT[c * 128 + k0 + k] = f2bf(W1a[(k0 + k) * 128 + c]);
    }
}

// exclusive scan of counts -> edge_off[0..B]; cursor = edge_off[0..B-1]
__global__ void k_scan(const int* __restrict__ counts, int* __restrict__ edge_off,
                       int* __restrict__ cursor, int B) {
    __shared__ int s[1024];
    int t = threadIdx.x;
    s[t] = (t < B) ? counts[t] : 0;
    __syncthreads();
    for (int d = 1; d < 1024; d <<= 1) {
        int v = (t >= d) ? s[t - d] : 0;
        __syncthreads();
        s[t] += v;
        __syncthreads();
    }
    if (t <= B) {
        int excl = (t == 0) ? 0 : s[t - 1];
        edge_off[t] = excl;
        if (t < B) cursor[t] = excl;
    }
}

// Fused: [0, nbh) counting-sort placement: perm[pos]=e, rows_s[pos]=ei[e]
// (ei read coalesced; 4 B scattered writes). [nbh, nbh+B): gx node sums.
__global__ __launch_bounds__(256) void k_pos(
    const int* __restrict__ gdst, const int* __restrict__ ei,
    int* __restrict__ cursor, int* __restrict__ perm, int* __restrict__ rows_s,
    const float* __restrict__ x, const int* __restrict__ node_off,
    float* __restrict__ gx, int E, int nbh) {
    __shared__ int cnt[NBMAX];
    __shared__ int basep[NBMAX];
    __shared__ float part[4][64];
    const int bid = blockIdx.x, t = threadIdx.x;
    if (bid < nbh) {
        for (int b = t; b < NBMAX; b += 256) cnt[b] = 0;
        __syncthreads();
        int blk = bid * 4096;
        int g[16], rk[16];
#pragma unroll
        for (int i = 0; i < 16; ++i) {
            int e = blk + i * 256 + t;
            g[i] = (e < E) ? gdst[e] : -1;
            rk[i] = (g[i] >= 0) ? atomicAdd(&cnt[g[i]], 1) : 0;
        }
        __syncthreads();
        for (int b = t; b < NBMAX; b += 256) {
            int c = cnt[b];
            basep[b] = c ? atomicAdd(&cursor[b], c) : 0;
        }
        __syncthreads();
#pragma unroll
        for (int i = 0; i < 16; ++i) {
            int e = blk + i * 256 + t;
            if (g[i] >= 0) {
                int pos = basep[g[i]] + rk[i];
                perm[pos] = e;
                rows_s[pos] = ei[e];
            }
        }
    } else {
        int g = bid - nbh;
        int lane = t & 63, wave = t >> 6;
        int n0 = node_off[g], n1 = node_off[g + 1];
        float a = 0.f;
        for (int n = n0 + wave; n < n1; n += 4) a += x[(size_t)n * 64 + lane];
        part[wave][lane] = a;
        __syncthreads();
        if (wave == 0)
            gx[g * 64 + lane] =
                (part[0][lane] + part[1][lane]) + (part[2][lane] + part[3][lane]);
    }
}

// Fused gather + MFMA edge kernel, software-pipelined.
// One 512-thread block per graph; wave w owns tiles lo+w*16, stride 128.
// Pipeline: idx prefetched 2 tiles ahead, A-row data (xb bf16 + raw fp32 ea)
// 1 tile ahead; fp32->bf16 pack at compute time. ea-half MFMAs issue first.
__global__ __launch_bounds__(512) void k_edges2(
    const short* __restrict__ xb, const float* __restrict__ ea,
    const int* __restrict__ rows_s, const int* __restrict__ perm,
    const int* __restrict__ edge_off, const short* __restrict__ WT,
    const float* __restrict__ b1a, float* __restrict__ Sg, float* __restrict__ Qg) {
    const int g = blockIdx.x;
    const int lane = threadIdx.x & 63, wave = threadIdx.x >> 6;
    const int m = lane & 15, quad = lane >> 4;

    bf16x8 Wf[4][8];
#pragma unroll
    for (int t = 0; t < 8; ++t)
#pragma unroll
        for (int ks = 0; ks < 4; ++ks)
            Wf[ks][t] = *(const bf16x8*)(WT + (t * 16 + m) * 128 + ks * 32 + quad * 8);
    float bb[8];
#pragma unroll
    for (int t = 0; t < 8; ++t) bb[t] = b1a[t * 16 + m];

    const int lo = edge_off[g], hi = edge_off[g + 1];

    float accS[8] = {0, 0, 0, 0, 0, 0, 0, 0};
    float accQ[8] = {0, 0, 0, 0, 0, 0, 0, 0};

    int b = lo + wave * 16;
    const bool active = (b < hi);
    if (active) {
        // ---- pipeline prologue ----
        int i0 = min(b + m, hi - 1);
        int r0 = rows_s[i0], p0 = perm[i0];
        int i1 = min(b + 128 + m, hi - 1);
        int r1 = rows_s[i1], p1 = perm[i1];
        const short* xr0 = xb + (size_t)r0 * 64;
        bf16x8 X0 = *(const bf16x8*)(xr0 + quad * 8);
        bf16x8 X1 = *(const bf16x8*)(xr0 + 32 + quad * 8);
        const float* er0 = ea + (size_t)p0 * 64;
        f32x4 P0 = *(const f32x4*)(er0 + quad * 8);
        f32x4 P1 = *(const f32x4*)(er0 + quad * 8 + 4);
        f32x4 P2 = *(const f32x4*)(er0 + 32 + quad * 8);
        f32x4 P3 = *(const f32x4*)(er0 + 32 + quad * 8 + 4);

        while (b < hi) {
            const int bn = b + 128;
            // idx prefetch (2 tiles ahead)
            int i2 = min(bn + 128 + m, hi - 1);
            int r2 = rows_s[i2], p2 = perm[i2];
            // A-data prefetch (1 tile ahead) — clamped-safe even past hi
            const short* xrn = xb + (size_t)r1 * 64;
            bf16x8 Xn0 = *(const bf16x8*)(xrn + quad * 8);
            bf16x8 Xn1 = *(const bf16x8*)(xrn + 32 + quad * 8);
            const float* ern = ea + (size_t)p1 * 64;
            f32x4 Q0 = *(const f32x4*)(ern + quad * 8);
            f32x4 Q1 = *(const f32x4*)(ern + quad * 8 + 4);
            f32x4 Q2 = *(const f32x4*)(ern + 32 + quad * 8);
            f32x4 Q3 = *(const f32x4*)(ern + 32 + quad * 8 + 4);

            // ---- compute current tile ----
            bf16x8 A2 = pack8(P0, P1);
            bf16x8 A3 = pack8(P2, P3);
            if (b + 16 <= hi) {  // full tile
#pragma unroll
                for (int t = 0; t < 8; ++t) {
                    f32x4 c = {0.f, 0.f, 0.f, 0.f};
                    c = __builtin_amdgcn_mfma_f32_16x16x32_bf16(A2, Wf[2][t], c, 0, 0, 0);
                    c = __builtin_amdgcn_mfma_f32_16x16x32_bf16(A3, Wf[3][t], c, 0, 0, 0);
                    c = __builtin_amdgcn_mfma_f32_16x16x32_bf16(X0, Wf[0][t], c, 0, 0, 0);
                    c = __builtin_amdgcn_mfma_f32_16x16x32_bf16(X1, Wf[1][t], c, 0, 0, 0);
#pragma unroll
                    for (int r = 0; r < 4; ++r) {
                        float z = c[r] + bb[t];
                        float a = fmaf(SLOPE, fminf(z, 0.f), fmaxf(z, 0.f));
                        accS[t] += a;
                        accQ[t] = fmaf(a, a, accQ[t]);
                    }
                }
            } else {  // masked tail tile (per-wave at most once)
                float vf[4];
#pragma unroll
                for (int r = 0; r < 4; ++r)
                    vf[r] = ((b + quad * 4 + r) < hi) ? 1.f : 0.f;
#pragma unroll
                for (int t = 0; t < 8; ++t) {
                    f32x4 c = {0.f, 0.f, 0.f, 0.f};
                    c = __builtin_amdgcn_mfma_f32_16x16x32_bf16(A2, Wf[2][t], c, 0, 0, 0);
                    c = __builtin_amdgcn_mfma_f32_16x16x32_bf16(A3, Wf[3][t], c, 0, 0, 0);
                    c = __builtin_amdgcn_mfma_f32_16x16x32_bf16(X0, Wf[0][t], c, 0, 0, 0);
                    c = __builtin_amdgcn_mfma_f32_16x16x32_bf16(X1, Wf[1][t], c, 0, 0, 0);
#pragma unroll
                    for (int r = 0; r < 4; ++r) {
                        float z = c[r] + bb[t];
                        float a = fmaf(SLOPE, fminf(z, 0.f), fmaxf(z, 0.f)) * vf[r];
                        accS[t] += a;
                        accQ[t] = fmaf(a, a, accQ[t]);
                    }
                }
            }
            // ---- rotate pipeline registers ----
            X0 = Xn0; X1 = Xn1;
            P0 = Q0; P1 = Q1; P2 = Q2; P3 = Q3;
            r1 = r2; p1 = p2;
            b = bn;
        }
        // ---- epilogue: cross-quad reduce, flush ----
#pragma unroll
        for (int t = 0; t < 8; ++t) {
            float s = accS[t];
            s += __shfl_xor(s, 16);
            s += __shfl_xor(s, 32);
            float q = accQ[t];
            q += __shfl_xor(q, 16);
            q += __shfl_xor(q, 32);
            if (quad == 0) {
                atomicAdd(&Sg[g * 128 + t * 16 + m], s);
                atomicAdd(&Qg[g * 128 + t * 16 + m], q);
            }
        }
    }
}

// Partial reduction of Sg/Qg over graphs (25 blocks)
__global__ __launch_bounds__(128) void k_stats_part(const float* __restrict__ Sg,
                                                    const float* __restrict__ Qg,
                                                    float* __restrict__ Stot,
                                                    float* __restrict__ Qtot, int B) {
    int c = threadIdx.x;
    int per = (B + gridDim.x - 1) / gridDim.x;
    int g0 = blockIdx.x * per, g1 = min(g0 + per, B);
    float S = 0.f, Q = 0.f;
    for (int g = g0; g < g1; ++g) {
        S += Sg[g * 128 + c];
        Q += Qg[g * 128 + c];
    }
    atomicAdd(&Stot[c], S);
    atomicAdd(&Qtot[c], Q);
}

// T = Sg*sc + cg*sh (sc/sh from Stot/Qtot); ga = T@W2a + cg*b2a;
// a1 = leaky([gx,ga]@W1b + b1b); accumulate BN1b stats.
__global__ __launch_bounds__(128) void k_g1(
    const float* __restrict__ Sg, const float* __restrict__ Stot,
    const float* __restrict__ Qtot, const float* __restrict__ gx,
    const int* __restrict__ edge_off, const float* __restrict__ g1a,
    const float* __restrict__ be1a, const float* __restrict__ W2a,
    const float* __restrict__ b2a, const float* __restrict__ W1b,
    const float* __restrict__ b1b, float* __restrict__ a1,
    float* __restrict__ sum1, float* __restrict__ sumsq1, float invE) {
    __shared__ float T[128];
    __shared__ float gcat[192];
    int g = blockIdx.x, c = threadIdx.x;
    float mn = Stot[c] * invE;
    float v = Qtot[c] * invE - mn * mn;
    float sc = g1a[c] * rsqrtf(v + EPS);
    float sh = be1a[c] - mn * sc;
    float cg = (float)(edge_off[g + 1] - edge_off[g]);
    T[c] = Sg[g * 128 + c] * sc + cg * sh;
    if (c < 64) gcat[c] = gx[g * 64 + c];
    __syncthreads();
    float ga = cg * b2a[c];
#pragma unroll 8
    for (int k = 0; k < 128; ++k) ga = fmaf(T[k], W2a[k * 128 + c], ga);
    gcat[64 + c] = ga;
    __syncthreads();
    float z = b1b[c];
#pragma unroll 8
    for (int k = 0; k < 192; ++k) z = fmaf(gcat[k], W1b[k * 128 + c], z);
    float av = leaky(z);
    a1[g * 128 + c] = av;
    atomicAdd(&sum1[c], av);
    atomicAdd(&sumsq1[c], av * av);
}

// hnorm = BN(a_prev); z = hnorm@W + b; optional leaky + next-stats.
__global__ __launch_bounds__(128) void k_bn_lin(
    const float* __restrict__ a_prev, const float* __restrict__ sum,
    const float* __restrict__ sumsq, const float* __restrict__ gma,
    const float* __restrict__ bta, const float* __restrict__ W,
    const float* __restrict__ b, float* __restrict__ a_out,
    float* __restrict__ sum_out, float* __restrict__ sumsq_out, float invB,
    int do_leaky) {
    __shared__ float hs[128];
    int g = blockIdx.x, c = threadIdx.x;
    float mn = sum[c] * invB;
    float v = sumsq[c] * invB - mn * mn;
    float sc = gma[c] * rsqrtf(v + EPS);
    float sh = bta[c] - mn * sc;
    hs[c] = a_prev[g * 128 + c] * sc + sh;
    __syncthreads();
    float z = b[c];
#pragma unroll 8
    for (int k = 0; k < 128; ++k) z = fmaf(hs[k], W[k * 128 + c], z);
    if (do_leaky) {
        z = leaky(z);
        a_out[g * 128 + c] = z;
        atomicAdd(&sum_out[c], z);
        atomicAdd(&sumsq_out[c], z * z);
    } else {
        a_out[g * 128 + c] = z;
    }
}

extern "C" void kernel_launch(void* const* d_in, const int* in_sizes, int n_in,
                              void* d_out, int out_size, void* d_ws, size_t ws_size,
                              hipStream_t stream) {
    const float* x    = (const float*)d_in[0];
    const int*   ei   = (const int*)d_in[1];
    const float* ea   = (const float*)d_in[2];
    const int*   batch= (const int*)d_in[4];
    const float* W1a  = (const float*)d_in[5];
    const float* b1a  = (const float*)d_in[6];
    const float* g1a  = (const float*)d_in[7];
    const float* be1a = (const float*)d_in[8];
    const float* W2a  = (const float*)d_in[9];
    const float* b2a  = (const float*)d_in[10];
    const float* W1b  = (const float*)d_in[11];
    const float* b1b  = (const float*)d_in[12];
    const float* g1b  = (const float*)d_in[13];
    const float* be1b = (const float*)d_in[14];
    const float* W2b  = (const float*)d_in[15];
    const float* b2b  = (const float*)d_in[16];
    const float* g2b  = (const float*)d_in[17];
    const float* be2b = (const float*)d_in[18];
    const float* W3b  = (const float*)d_in[19];
    const float* b3b  = (const float*)d_in[20];

    const int N = in_sizes[0] / 64;
    const int E = in_sizes[1] / 2;
    const int B = in_sizes[3];

    char* ws = (char*)d_ws;
    size_t off = 0;
    auto alloc = [&](size_t bytes) -> char* {
        char* p = ws + off;
        off = (off + bytes + 255) & ~(size_t)255;
        return p;
    };
    // ---- zeroed region (one memset) ----
    int*   counts = (int*)alloc((size_t)B * 4);
    float* Sg     = (float*)alloc((size_t)B * 128 * 4);
    float* Qg     = (float*)alloc((size_t)B * 128 * 4);
    float* sum1   = (float*)alloc(128 * 4);
    float* sumsq1 = (float*)alloc(128 * 4);
    float* sum2   = (float*)alloc(128 * 4);
    float* sumsq2 = (float*)alloc(128 * 4);
    float* Stot   = (float*)alloc(128 * 4);
    float* Qtot   = (float*)alloc(128 * 4);
    size_t zbytes = off;
    // ---- non-zeroed scratch ----
    short* xb      = (short*)alloc((size_t)N * 64 * 2);
    short* WT      = (short*)alloc(128 * 128 * 2);
    int*   gdst    = (int*)alloc((size_t)E * 4);
    int*   perm    = (int*)alloc((size_t)E * 4);
    int*   rows_s  = (int*)alloc((size_t)E * 4);
    int*   edge_off= (int*)alloc((size_t)(B + 1) * 4);
    int*   cursor  = (int*)alloc((size_t)B * 4);
    int*   node_off= (int*)alloc((size_t)(B + 1) * 4);
    float* gx      = (float*)alloc((size_t)B * 64 * 4);
    float* a1      = (float*)alloc((size_t)B * 128 * 4);
    float* a2      = (float*)alloc((size_t)B * 128 * 4);
    (void)ws_size;
    (void)n_in;

    hipMemsetAsync(ws, 0, zbytes, stream);

    const int nbx = (N * 16 + 255) / 256;
    const int nbh = (E + 4095) / 4096;
    const int nbn = (N + 255) / 256;
    k_prep<<<dim3(nbx + nbh + nbn + 1), dim3(256), 0, stream>>>(
        x, xb, W1a, WT, ei, batch, gdst, counts, node_off, N, E, B, nbx, nbh, nbn);
    k_scan<<<dim3(1), dim3(1024), 0, stream>>>(counts, edge_off, cursor, B);
    k_pos<<<dim3(nbh + B), dim3(256), 0, stream>>>(gdst, ei, cursor, perm, rows_s,
                                                   x, node_off, gx, E, nbh);
    k_edges2<<<dim3(B), dim3(512), 0, stream>>>(xb, ea, rows_s, perm, edge_off,
                                                WT, b1a, Sg, Qg);
    k_stats_part<<<dim3(25), dim3(128), 0, stream>>>(Sg, Qg, Stot, Qtot, B);
    k_g1<<<dim3(B), dim3(128), 0, stream>>>(Sg, Stot, Qtot, gx, edge_off, g1a, be1a,
                                            W2a, b2a, W1b, b1b, a1, sum1, sumsq1,
                                            1.0f / (float)E);
    k_bn_lin<<<dim3(B), dim3(128), 0, stream>>>(a1, sum1, sumsq1, g1b, be1b, W2b,
                                                b2b, a2, sum2, sumsq2,
                                                1.0f / (float)B, 1);
    k_bn_lin<<<dim3(B), dim3(128), 0, stream>>>(a2, sum2, sumsq2, g2b, be2b, W3b,
                                                b3b, (float*)d_out, nullptr, nullptr,
                                                1.0f / (float)B, 0);
}